// Round 11
// baseline (359.855 us; speedup 1.0000x reference)
//
#include <hip/hip_runtime.h>

// NOE net sequential scan, round 11.
// Pure-scalar minimal-instruction rewrite of round 3 (best, 318us).
// Machine model from rounds 1-10: kernel is total-VALU-instruction bound
// (~1.9us per instr/step); v2 ext-vector code scalarizes with ~2x overhead;
// inline-asm packed ops corrupt trans results (hazard recognizer skips
// INLINEASM) -- so: plain scalar f32, hw v_exp/v_rcp, no vector types in
// the hot loop, no inline asm.
// o-reduction DEFERRED: per-lane opart[s] kept in regs across the 8-step
// block, then one wave-private LDS 8x8 transpose (stride 12 -> conflict-free)
// + 7 adds; only the h-reduction (2x red8, DPP) stays on the recurrence path.
// Structure: 8 lanes/row, lane owns 4 units/MLP, NCHUNK=4/WARM=64 contractive
// time-chunking, layer-1 weights pre-scaled by -log2e.

#define T_LEN 2048
#define NCHUNK 4
#define WARM 64

template <int CTRL>
__device__ __forceinline__ float dpp_add(float v) {
  return v + __int_as_float(__builtin_amdgcn_update_dpp(
                 0, __float_as_int(v), CTRL, 0xF, 0xF, true));
}

// sum across each aligned 8-lane group; result in all 8 lanes
__device__ __forceinline__ float red8(float v) {
  v = dpp_add<0xB1>(v);   // quad_perm [1,0,3,2] : xor 1
  v = dpp_add<0x4E>(v);   // quad_perm [2,3,0,1] : xor 2
  v = dpp_add<0x141>(v);  // row_half_mirror     : xor 4 within 8
  return v;
}

__global__ __launch_bounds__(256) void noenet_scan(
    const float* __restrict__ x,
    const float* __restrict__ l1w, const float* __restrict__ l1b,
    const float* __restrict__ l2w, const float* __restrict__ l2b,
    const float* __restrict__ r1w, const float* __restrict__ r1b,
    const float* __restrict__ r2w, const float* __restrict__ r2b,
    float* __restrict__ y, int B) {
  __shared__ float lds[256 * 12];  // 8 opartials/thread, stride 12 (pad)

  const unsigned tid = blockIdx.x * blockDim.x + threadIdx.x;
  const unsigned lt = threadIdx.x;          // lane-in-block
  const unsigned g = tid & 7;
  const unsigned grp = lt & ~7u;            // first thread of this row group
  const unsigned rowc = tid >> 3;
  const unsigned b = rowc & (unsigned)(B - 1);  // B is a power of two (8192)
  const unsigned c = rowc / (unsigned)B;        // chunk index
  if (c >= NCHUNK) return;

  const float NL2E = -1.44269504088896340736f;
  const int ia = (int)g * 4;  // this lane's first hidden unit

  // ---- per-lane weights, all scalar regs (layer 1 pre-scaled by -log2e)
  float zw[4][4], zb[4], ow[4];
  float rw[4][4], rb[4], q0[4], q1[4];
#pragma unroll
  for (int i = 0; i < 4; ++i) {
    const float4 zr = *(const float4*)(l1w + (ia + i) * 4);
    zw[i][0] = zr.x * NL2E; zw[i][1] = zr.y * NL2E;
    zw[i][2] = zr.z * NL2E; zw[i][3] = zr.w * NL2E;
    zb[i] = l1b[ia + i] * NL2E;
    ow[i] = l2w[ia + i];
    const float4 rr = *(const float4*)(r1w + (ia + i) * 4);
    rw[i][0] = rr.x * NL2E; rw[i][1] = rr.y * NL2E;
    rw[i][2] = rr.z * NL2E; rw[i][3] = rr.w * NL2E;
    rb[i] = r1b[ia + i] * NL2E;
    q0[i] = r2w[ia + i];
    q1[i] = r2w[32 + ia + i];
  }
  const float ob  = l2b[0];
  const float hb0 = r2b[0];
  const float hb1 = r2b[1];

  const float* xb = x + (size_t)b * T_LEN;
  float* yb = y + (size_t)b * (T_LEN - 1);

  // ---- chunk bounds
  const int wstart = (int)c * (T_LEN / NCHUNK);              // first stored t
  const int t0 = (c == 0) ? 0 : wstart - WARM;               // multiple of 8
  const int t_end = (c == NCHUNK - 1) ? (T_LEN - 1) : wstart + (T_LEN / NCHUNK);
  const int steps = t_end - t0;
  const int nb = steps >> 3;  // full 8-step blocks (tail only in last chunk)

  float h0 = 0.0f, h1 = 0.0f;
  float op[8];  // per-lane o-partials for the current 8-step block

  // one step; returns this lane's UNREDUCED o-partial
  auto step = [&](float u0, float u1) -> float {
    float za[4], ra[4], zs[4], hs[4];
#pragma unroll
    for (int i = 0; i < 4; ++i) {
      za[i] = fmaf(zw[i][2], h0, fmaf(zw[i][3], h1,
              fmaf(zw[i][0], u0, fmaf(zw[i][1], u1, zb[i]))));
      ra[i] = fmaf(rw[i][2], h0, fmaf(rw[i][3], h1,
              fmaf(rw[i][0], u0, fmaf(rw[i][1], u1, rb[i]))));
    }
#pragma unroll
    for (int i = 0; i < 4; ++i) {
      zs[i] = __builtin_amdgcn_rcpf(1.0f + __builtin_amdgcn_exp2f(za[i]));
      hs[i] = __builtin_amdgcn_rcpf(1.0f + __builtin_amdgcn_exp2f(ra[i]));
    }
    float opart = zs[0] * ow[0];
    float p0    = hs[0] * q0[0];
    float p1    = hs[0] * q1[0];
#pragma unroll
    for (int i = 1; i < 4; ++i) {
      opart = fmaf(zs[i], ow[i], opart);
      p0    = fmaf(hs[i], q0[i], p0);
      p1    = fmaf(hs[i], q1[i], p1);
    }
    h0 = red8(p0) + hb0;
    h1 = red8(p1) + hb1;
    return opart;
  };

  // deferred o-reduction for one block: 8x8 transpose via wave-private LDS
  auto flush_o = [&](int t, int nvalid) {
    float4* wp = (float4*)(lds + lt * 12);
    wp[0] = make_float4(op[0], op[1], op[2], op[3]);
    wp[1] = make_float4(op[4], op[5], op[6], op[7]);
    float s = lds[(grp + 0) * 12 + g];
#pragma unroll
    for (int j = 1; j < 8; ++j) s += lds[(grp + j) * 12 + g];
    if (t >= wstart && (int)g < nvalid) yb[t + g] = s + ob;
  };

  float4 cur = *(const float4*)(xb + t0);
  for (int blk = 0; blk < nb; ++blk) {
    const int t = t0 + blk * 8;
    const float4 mid = *(const float4*)(xb + t + 4);
    const float4 nxt = *(const float4*)(xb + t + 8);
    const float u[9] = {cur.x, cur.y, cur.z, cur.w,
                        mid.x, mid.y, mid.z, mid.w, nxt.x};
#pragma unroll
    for (int s = 0; s < 8; ++s) op[s] = step(u[s], u[s + 1]);
    flush_o(t, 8);
    cur = nxt;
  }
  if (steps & 7) {  // last chunk only: 7 tail steps (t = 2040..2046)
    const int t = t0 + nb * 8;
    const float4 mid = *(const float4*)(xb + t + 4);
    const float u[8] = {cur.x, cur.y, cur.z, cur.w,
                        mid.x, mid.y, mid.z, mid.w};
    op[7] = 0.0f;
#pragma unroll
    for (int s = 0; s < 7; ++s) op[s] = step(u[s], u[s + 1]);
    flush_o(t, 7);
  }
}

extern "C" void kernel_launch(void* const* d_in, const int* in_sizes, int n_in,
                              void* d_out, int out_size, void* d_ws, size_t ws_size,
                              hipStream_t stream) {
  const float* x   = (const float*)d_in[0];
  const float* l1w = (const float*)d_in[1];
  const float* l1b = (const float*)d_in[2];
  const float* l2w = (const float*)d_in[3];
  const float* l2b = (const float*)d_in[4];
  const float* r1w = (const float*)d_in[5];
  const float* r1b = (const float*)d_in[6];
  const float* r2w = (const float*)d_in[7];
  const float* r2b = (const float*)d_in[8];
  float* y = (float*)d_out;

  const int B = in_sizes[0] / T_LEN;           // 8192
  const long threads = (long)B * 8 * NCHUNK;   // 8 lanes/row x NCHUNK chunks
  const int block = 256;
  const int grid = (int)((threads + block - 1) / block);

  noenet_scan<<<grid, block, 0, stream>>>(x, l1w, l1b, l2w, l2b,
                                          r1w, r1b, r2w, r2b, y, B);
}